// Round 11
// baseline (42.757 us; speedup 1.0000x reference)
//
#include <hip/hip_runtime.h>

#define TPB 256                        // 4 waves; quarter-row lanes
#define CHUNK_ROWS 64
#define ROW_F 25
#define CHUNK_FA (CHUNK_ROWS * ROW_F)  // 1600 floats per array per chunk
#define CHUNK_F4A (CHUNK_FA / 4)       // 400 float4 per array
#define CHUNK_F4 (2 * CHUNK_F4A)       // 800 float4 combined

// Slim judge for ONE group: ranks of out == ranks of pre (softmax monotone);
// "within" in scaled form |3*e_i - t_i*S| <= 0.09*S (no divide in the chain).
__device__ __forceinline__ void judge_group(const float* __restrict__ p,
                                            const float* __restrict__ t,
                                            int& calc, int& acc) {
    const float GAPv = 0.03f;   // 3 * 0.01
    float p0 = p[0], p1 = p[1], p2 = p[2], p3 = p[3];
    float t0 = t[0], t1 = t[1], t2 = t[2], t3 = t[3];

    float m  = fmaxf(fmaxf(p0, p1), fmaxf(p2, p3));
    float e0 = __expf(p0 - m), e1 = __expf(p1 - m);
    float e2 = __expf(p2 - m), e3 = __expf(p3 - m);
    float S  = (e0 + e1) + (e2 + e3);
    float thr = 0.09f * S;
    float w0 = fmaf(3.0f, e0, -t0 * S);
    float w1 = fmaf(3.0f, e1, -t1 * S);
    float w2 = fmaf(3.0f, e2, -t2 * S);
    float w3 = fmaf(3.0f, e3, -t3 * S);
    bool within = fabsf(w0) <= thr && fabsf(w1) <= thr &&
                  fabsf(w2) <= thr && fabsf(w3) <= thr;

    // stable ranks of p (== ranks of out). g_ij = (p_j < p_i), i<j.
    int g01 = p1 < p0, g02 = p2 < p0, g03 = p3 < p0;
    int g12 = p2 < p1, g13 = p3 < p1, g23 = p3 < p2;
    int ro0 = g01 + g02 + g03;
    int ro1 = 1 - g01 + g12 + g13;
    int ro2 = 2 - g02 - g12 + g23;
    int ro3 = 3 - g03 - g13 - g23;

    int h01 = t1 < t0, h02 = t2 < t0, h03 = t3 < t0;
    int h12 = t2 < t1, h13 = t3 < t1, h23 = t3 < t2;
    int rt0 = h01 + h02 + h03;
    int rt1 = 1 - h01 + h12 + h13;
    int rt2 = 2 - h02 - h12 + h23;
    int rt3 = 3 - h03 - h13 - h23;

    // sorted target values (ascending): st0 <= st1 <= st2
    float l01 = fminf(t0, t1), x01 = fmaxf(t0, t1);
    float l23 = fminf(t2, t3), x23 = fmaxf(t2, t3);
    float st0 = fminf(l01, l23), mlo = fmaxf(l01, l23);
    float mhi = fminf(x01, x23);
    float st1 = fminf(mlo, mhi), st2 = fmaxf(mlo, mhi);
    float d1 = st1 - st0;
    float d2 = st2 - st1;

    bool jump = within && (
        ((d1 < GAPv) & (d2 < GAPv)) ||
        ((d1 < GAPv) & (ro2 == rt2)) ||
        ((d2 < GAPv) & (ro0 == rt0)));

    int nz = (t0 == 0.0f) + (t1 == 0.0f) + (t2 == 0.0f) + (t3 == 0.0f);
    bool match_all = (ro0 == rt0) & (ro1 == rt1) & (ro2 == rt2) & (ro3 == rt3);

    bool s2 = ((ro0 == 2) & (rt0 == 2)) | ((ro1 == 2) & (rt1 == 2)) |
              ((ro2 == 2) & (rt2 == 2)) | ((ro3 == 2) & (rt3 == 2));
    bool s3 = ((ro0 == 3) & (rt0 == 3)) | ((ro1 == 3) & (rt1 == 3)) |
              ((ro2 == 3) & (rt2 == 3)) | ((ro3 == 3) & (rt3 == 3));

    bool c_lt2 = !jump & (nz < 2);
    bool c_eq2 = !jump & (nz == 2) & s2 & s3;
    bool c_eq3 = !jump & (nz == 3) & (ro3 == 3);

    calc += (jump | c_lt2 | c_eq2 | c_eq3) ? 1 : 0;
    acc  += (jump | (c_lt2 & match_all) | c_eq2 | c_eq3) ? 1 : 0;
}

__global__ __launch_bounds__(TPB, 8)
void recall_main_kernel(const float* __restrict__ pre,
                        const float* __restrict__ tar,
                        float* __restrict__ partial,
                        int B, int nchunks) {
    // one 64-row chunk: pre floats [0,1600), tar floats [1600,3200) -> 12.8 KB
    __shared__ __align__(16) float s_data[2 * CHUNK_FA];
    __shared__ float s_red[8];

    const int t    = threadIdx.x;
    const int lane = t & 63;
    const int wid  = t >> 6;
    const int total4 = (B * ROW_F) >> 2;   // per-array float4 count

    const float4* pre4 = (const float4*)pre;
    const float4* tar4 = (const float4*)tar;
    float4* s4 = (float4*)s_data;

    // quarter-row mapping: lanes l, l+16, l+32, l+48 share row (wid*16 + (l&15));
    // quarter q judges groups {0,1},{2,3},{4},{5} -> float offsets 0,8,16,20
    const int row_local = (wid << 4) | (lane & 15);
    const int q    = lane >> 4;
    const int qoff = (q < 3) ? (q << 3) : 20;

    float csum = 0.0f, vsum = 0.0f;

    for (int c = blockIdx.x; c < nchunks; c += gridDim.x) {
        __syncthreads();   // previous iteration's LDS reads done before overwrite

        const int base4 = c * CHUNK_F4A;

        if (base4 + CHUNK_F4A <= total4) {
            // full chunk: guard-free combined staging (800 f4: pre then tar)
#pragma unroll
            for (int k = 0; k < 3; ++k) {
                int j = k * TPB + t;
                const float4* src = (j < CHUNK_F4A)
                    ? (pre4 + base4 + j)
                    : (tar4 + base4 + (j - CHUNK_F4A));
                s4[j] = *src;
            }
            if (t < CHUNK_F4 - 3 * TPB) {          // remaining 32 f4 (tar)
                int j = 3 * TPB + t;
                s4[j] = tar4[base4 + (j - CHUNK_F4A)];
            }
        } else {
            // tail chunk: guarded (clamped entries belong to rows >= B, unused)
#pragma unroll
            for (int k = 0; k < 4; ++k) {
                int j = k * TPB + t;
                if (j < CHUNK_F4) {
                    int gi = base4 + ((j < CHUNK_F4A) ? j : (j - CHUNK_F4A));
                    if (gi >= total4) gi = total4 - 1;
                    s4[j] = (j < CHUNK_F4A) ? pre4[gi] : tar4[gi];
                }
            }
        }
        __syncthreads();

        int row = c * CHUNK_ROWS + row_local;
        if (row < B) {
            const float* rp = s_data + row_local * ROW_F + qoff;
            const float* rt = rp + CHUNK_FA;
            int calc = 0, acc = 0;
            judge_group(rp, rt, calc, acc);
            if (q < 2) judge_group(rp + 4, rt + 4, calc, acc);
            // merge the 4 lanes of this row: two packed shuffles
            int pack = (acc << 8) | calc;
            pack += __shfl_xor(pack, 16);
            pack += __shfl_xor(pack, 32);
            calc = pack & 0xff;
            acc  = pack >> 8;
            if (q == 0 && calc > 0) {
                csum += __fdividef((float)acc, (float)calc);
                vsum += 1.0f;
            }
        }
    }

    // deterministic block reduction (4 waves)
#pragma unroll
    for (int off = 32; off > 0; off >>= 1) {
        csum += __shfl_down(csum, off);
        vsum += __shfl_down(vsum, off);
    }
    if (lane == 0) { s_red[wid] = csum; s_red[4 + wid] = vsum; }
    __syncthreads();
    if (t == 0) {
        partial[2 * blockIdx.x]     = s_red[0] + s_red[1] + s_red[2] + s_red[3];
        partial[2 * blockIdx.x + 1] = s_red[4] + s_red[5] + s_red[6] + s_red[7];
    }
}

__global__ __launch_bounds__(256)
void recall_finalize_kernel(const float* __restrict__ partial, int n,
                            float* __restrict__ out) {
    __shared__ float s_red[8];
    float c = 0.0f, v = 0.0f;
    for (int i = threadIdx.x; i < n; i += 256) {
        c += partial[2 * i];
        v += partial[2 * i + 1];
    }
#pragma unroll
    for (int off = 32; off > 0; off >>= 1) {
        c += __shfl_down(c, off);
        v += __shfl_down(v, off);
    }
    int wave = threadIdx.x >> 6;
    if ((threadIdx.x & 63) == 0) { s_red[wave] = c; s_red[4 + wave] = v; }
    __syncthreads();
    if (threadIdx.x == 0) {
        float cs = s_red[0] + s_red[1] + s_red[2] + s_red[3];
        float vs = s_red[4] + s_red[5] + s_red[6] + s_red[7];
        out[0] = (vs > 0.0f) ? (cs / vs) : 0.0f;
    }
}

extern "C" void kernel_launch(void* const* d_in, const int* in_sizes, int n_in,
                              void* d_out, int out_size, void* d_ws, size_t ws_size,
                              hipStream_t stream) {
    const float* pre = (const float*)d_in[0];
    const float* tar = (const float*)d_in[1];
    float* out = (float*)d_out;
    float* partial = (float*)d_ws;                 // up to 2048*2*4 = 16 KB

    int B = in_sizes[0] / ROW_F;
    int nchunks = (B + CHUNK_ROWS - 1) / CHUNK_ROWS;

    // exact one-round residency: 8 blocks/CU (wave cap) x 256 CU = 2048 blocks
    int grid = 2048;
    if (grid > nchunks) grid = nchunks;
    if (grid < 1) grid = 1;

    recall_main_kernel<<<grid, TPB, 0, stream>>>(pre, tar, partial, B, nchunks);
    recall_finalize_kernel<<<1, 256, 0, stream>>>(partial, grid, out);
}